// Round 9
// baseline (164.881 us; speedup 1.0000x reference)
//
#include <hip/hip_runtime.h>
#include <stdint.h>

#define NB 4
#define NC 17
#define HH 8
#define SS 512
#define DD 64

typedef __attribute__((ext_vector_type(8))) short bf16x8;
typedef __attribute__((ext_vector_type(16))) float f32x16;

// ws layout (bytes):
//   W1mbf : [17][8][64][64] bf16 = 1,114,112
//   Tg    : [64 bh][5 P][512 j][64 m] bf16 = 20,971,520
#define WS_W1 0
#define WS_T  1114112

__device__ __forceinline__ unsigned short f2bf(float f) {
  unsigned int x; __builtin_memcpy(&x, &f, 4);
  return (unsigned short)((x + 0x7fff + ((x >> 16) & 1)) >> 16);
}
__device__ __forceinline__ bf16x8 cvt8(float4 a, float4 b) {
  union { bf16x8 v; unsigned short u[8]; } t;
  t.u[0] = f2bf(a.x); t.u[1] = f2bf(a.y); t.u[2] = f2bf(a.z); t.u[3] = f2bf(a.w);
  t.u[4] = f2bf(b.x); t.u[5] = f2bf(b.y); t.u[6] = f2bf(b.z); t.u[7] = f2bf(b.w);
  return t.v;
}
#define ZERO16 {0.f,0.f,0.f,0.f,0.f,0.f,0.f,0.f,0.f,0.f,0.f,0.f,0.f,0.f,0.f,0.f}

// ---- K0: W1mbf[c][h][.] = sum_B W1[B][h][.] * softmax(alpha, axis=B)[c,B,h] ----
__global__ __launch_bounds__(256) void k_prep(const float* __restrict__ W1,
                                              const float* __restrict__ alpha,
                                              unsigned short* __restrict__ W1mbf) {
  int tid = threadIdx.x;
  int c = blockIdx.x >> 3, hh = blockIdx.x & 7;
  __shared__ float sm[NB];
  if (tid == 0) {
    float a[NB], mx = -1e30f;
    for (int B = 0; B < NB; B++) { a[B] = alpha[(c * NB + B) * HH + hh]; mx = fmaxf(mx, a[B]); }
    float s = 0.f;
    for (int B = 0; B < NB; B++) { a[B] = __expf(a[B] - mx); s += a[B]; }
    for (int B = 0; B < NB; B++) sm[B] = a[B] / s;
  }
  __syncthreads();
  float s0 = sm[0], s1 = sm[1], s2 = sm[2], s3 = sm[3];
  for (int idx = tid; idx < DD * DD; idx += blockDim.x) {
    float v = W1[((0 * HH + hh) * DD * DD) + idx] * s0 +
              W1[((1 * HH + hh) * DD * DD) + idx] * s1 +
              W1[((2 * HH + hh) * DD * DD) + idx] * s2 +
              W1[((3 * HH + hh) * DD * DD) + idx] * s3;
    W1mbf[((size_t)(c * HH + hh)) * DD * DD + idx] = f2bf(v);
  }
}

// ---- K1: Tg[bh][P][j][m] = sum_n key[j][n] * W_{c(P,bj_j)}[m][n].
// 32x32x16 MFMA; compute class-0 + 4 candidate classes per plane, select
// per-element by the ROW's bj. No LDS, no barriers, no grouping.
// Grid: 64 bh x 8 (64-col groups). Wave = (32-col tile jt, 32-m half mh).
__global__ __launch_bounds__(256, 2) void k_T(const float* __restrict__ key,
                                              const int* __restrict__ bseq,
                                              const unsigned short* __restrict__ W1mbf,
                                              unsigned short* __restrict__ Tg) {
  int bx = blockIdx.x;
  int bh = bx & 63, jg = bx >> 6;
  int b = bh >> 3, h = bh & 7;
  int tid = threadIdx.x, wave = tid >> 6, lane = tid & 63;
  int jt = wave & 1, mh = wave >> 1;
  int j0 = jg * 64 + jt * 32, m0 = mh * 32;
  int l31 = lane & 31, lhi = lane >> 5;

  // A-fragments: key rows j0..j0+31 (fp32 -> bf16), 4 k-chunks of 16
  bf16x8 A[4];
  const float* kb = &key[((size_t)(bh * SS) + j0 + l31) * DD + lhi * 8];
#pragma unroll
  for (int ch = 0; ch < 4; ch++) {
    const float* p = kb + ch * 16;
    A[ch] = cvt8(*(const float4*)p, *(const float4*)(p + 4));
  }
  // per-acc-reg row bj
  int bjr[16];
#pragma unroll
  for (int r = 0; r < 16; r++) {
    int row = (r & 3) + 8 * (r >> 2) + 4 * lhi;
    bjr[r] = bseq[b * SS + j0 + row];
  }
  unsigned short* Tp = Tg + (size_t)bh * 5 * SS * DD;

  // class-0 acc (used for plane 0 entirely and bj==0 rows of planes 1..4)
  f32x16 acc0 = ZERO16;
#pragma unroll
  for (int ch = 0; ch < 4; ch++) {
    const unsigned short* wp =
        &W1mbf[((size_t)(0 * HH + h)) * DD * DD + (m0 + l31) * DD + ch * 16 + lhi * 8];
    bf16x8 Bf = *(const bf16x8*)wp;
    acc0 = __builtin_amdgcn_mfma_f32_32x32x16_bf16(A[ch], Bf, acc0, 0, 0, 0);
  }
#pragma unroll
  for (int r = 0; r < 16; r++) {
    int row = (r & 3) + 8 * (r >> 2) + 4 * lhi;
    Tp[((size_t)(0 * SS) + j0 + row) * DD + m0 + l31] = f2bf(acc0[r]);
  }

#pragma unroll
  for (int P = 1; P <= 4; P++) {
    int cb = (P - 1) * NB;  // classes cb+1 .. cb+4
    f32x16 c1 = ZERO16, c2 = ZERO16, c3 = ZERO16, c4 = ZERO16;
#pragma unroll
    for (int ch = 0; ch < 4; ch++) {
      size_t woff = (size_t)(m0 + l31) * DD + ch * 16 + lhi * 8;
      const unsigned short* w1 = &W1mbf[((size_t)((cb + 1) * HH + h)) * DD * DD + woff];
      const unsigned short* w2 = &W1mbf[((size_t)((cb + 2) * HH + h)) * DD * DD + woff];
      const unsigned short* w3 = &W1mbf[((size_t)((cb + 3) * HH + h)) * DD * DD + woff];
      const unsigned short* w4 = &W1mbf[((size_t)((cb + 4) * HH + h)) * DD * DD + woff];
      bf16x8 B1 = *(const bf16x8*)w1, B2 = *(const bf16x8*)w2;
      bf16x8 B3 = *(const bf16x8*)w3, B4 = *(const bf16x8*)w4;
      c1 = __builtin_amdgcn_mfma_f32_32x32x16_bf16(A[ch], B1, c1, 0, 0, 0);
      c2 = __builtin_amdgcn_mfma_f32_32x32x16_bf16(A[ch], B2, c2, 0, 0, 0);
      c3 = __builtin_amdgcn_mfma_f32_32x32x16_bf16(A[ch], B3, c3, 0, 0, 0);
      c4 = __builtin_amdgcn_mfma_f32_32x32x16_bf16(A[ch], B4, c4, 0, 0, 0);
    }
#pragma unroll
    for (int r = 0; r < 16; r++) {
      int bj = bjr[r];
      float v = c1[r];
      v = (bj == 2) ? c2[r] : v;
      v = (bj == 3) ? c3[r] : v;
      v = (bj == 4) ? c4[r] : v;
      v = (bj == 0) ? acc0[r] : v;
      int row = (r & 3) + 8 * (r >> 2) + 4 * lhi;
      Tp[((size_t)(P * SS) + j0 + row) * DD + m0 + l31] = f2bf(v);
    }
  }
}

// ---- K2: out[bh][i][j] = sum_m q[i][m] * Tg[bh][bi_i][j][m].
// 32x32x16 MFMA, all 5 planes, per-element select by row bi. No LDS/barriers.
// Grid: 64 bh x 16 (32-row slabs). Wave = 128-col strip (4 x 32-col tiles).
__global__ __launch_bounds__(256, 2) void k_scores(const float* __restrict__ query,
                                                   const int* __restrict__ bseq,
                                                   const unsigned short* __restrict__ Tg,
                                                   float* __restrict__ out) {
  int bx = blockIdx.x;
  int bh = bx & 63, slab = bx >> 6;
  int b = bh >> 3;
  int i0 = slab * 32;
  int tid = threadIdx.x, wave = tid >> 6, lane = tid & 63;
  int l31 = lane & 31, lhi = lane >> 5;
  int c0 = wave * 128;

  // A-fragments: q rows i0..i0+31
  bf16x8 A[4];
  const float* qb = &query[((size_t)(bh * SS) + i0 + l31) * DD + lhi * 8];
#pragma unroll
  for (int ch = 0; ch < 4; ch++) {
    const float* p = qb + ch * 16;
    A[ch] = cvt8(*(const float4*)p, *(const float4*)(p + 4));
  }
  int bir[16];
#pragma unroll
  for (int r = 0; r < 16; r++) {
    int row = (r & 3) + 8 * (r >> 2) + 4 * lhi;
    bir[r] = bseq[b * SS + i0 + row];
  }
  const unsigned short* Tp = Tg + (size_t)bh * 5 * SS * DD;

  for (int ct = 0; ct < 4; ct++) {
    int j0 = c0 + ct * 32;
    f32x16 acc[5];
#pragma unroll
    for (int P = 0; P < 5; P++) {
      f32x16 z = ZERO16;
#pragma unroll
      for (int ch = 0; ch < 4; ch++) {
        const unsigned short* tp =
            &Tp[((size_t)(P * SS) + j0 + l31) * DD + ch * 16 + lhi * 8];
        bf16x8 Bf = *(const bf16x8*)tp;
        z = __builtin_amdgcn_mfma_f32_32x32x16_bf16(A[ch], Bf, z, 0, 0, 0);
      }
      acc[P] = z;
    }
#pragma unroll
    for (int r = 0; r < 16; r++) {
      int bi = bir[r];
      float v = acc[0][r];
      v = (bi == 1) ? acc[1][r] : v;
      v = (bi == 2) ? acc[2][r] : v;
      v = (bi == 3) ? acc[3][r] : v;
      v = (bi == 4) ? acc[4][r] : v;
      int row = (r & 3) + 8 * (r >> 2) + 4 * lhi;
      out[((size_t)(bh * SS) + i0 + row) * SS + j0 + l31] = v;
    }
  }
}

extern "C" void kernel_launch(void* const* d_in, const int* in_sizes, int n_in,
                              void* d_out, int out_size, void* d_ws, size_t ws_size,
                              hipStream_t stream) {
  const float* q = (const float*)d_in[0];
  const float* k = (const float*)d_in[1];
  const int* bseq = (const int*)d_in[2];
  const float* W1 = (const float*)d_in[3];
  const float* alpha = (const float*)d_in[4];
  float* out = (float*)d_out;
  char* ws = (char*)d_ws;
  unsigned short* W1mbf = (unsigned short*)(ws + WS_W1);
  unsigned short* Tg = (unsigned short*)(ws + WS_T);

  hipLaunchKernelGGL(k_prep, dim3(NC * HH), dim3(256), 0, stream, W1, alpha, W1mbf);
  hipLaunchKernelGGL(k_T, dim3(64 * 8), dim3(256), 0, stream, k, bseq, W1mbf, Tg);
  hipLaunchKernelGGL(k_scores, dim3(64 * 16), dim3(256), 0, stream, q, bseq, Tg, out);
}